// Round 7
// baseline (860.794 us; speedup 1.0000x reference)
//
#include <hip/hip_runtime.h>
#include <stdint.h>

// HashEmbedder (Instant-NGP multires hash grid), 16 levels, F=2, T=2^19,
// N = 2^21 points.
//
// Round-7 = round-6 with fine_kernel restructured for memory-level
// parallelism. Round-6 counters: VGPR=16, lines/cyc=0.53 -> latency-bound
// (compiler buffered ~3 gathers/wave). New structure: phase-1 issues ALL
// 32 gathers for 4 points (branch-free: 8B pair at h0&~1 + 4B scalar at
// h1 per corner-pair; even-bx scalar MSHR-merges into the pair's line so
// avg lines/pt stays ~6), phase-2 consumes. Bit-identical arithmetic.
//
//   pass 0 : pack f32 tables -> bf16x2 (4B/entry).
//   pass 0b: dense de-hashed tables for levels 0-2 (124 KB) and dense
//            x4-grouped tables for levels 3-6.
//   pass A : levels 0-2 via LDS-staged dense tables.
//   pass B : levels 3-6 via dense-x4 global tables.
//   pass C : levels 7-15 hashed, level-at-a-time, pair+scalar batched.
//   pass 2 : transpose level-major bf16x2 -> [N][32] f32.

constexpr int kLevels = 16;
constexpr int kPoints = 1 << 21;
constexpr uint32_t kTableSize = 1u << 19;
constexpr uint32_t kMask = kTableSize - 1u;
constexpr size_t kPackedBytes = (size_t)kLevels * kTableSize * 4;  // 32 MB
constexpr size_t kLvlOutBytes = (size_t)kLevels * kPoints * 4;     // 128 MB

typedef float f32x4 __attribute__((ext_vector_type(4)));
typedef uint32_t u32x4 __attribute__((ext_vector_type(4)));

// dense coarse (levels 0-2): entry counts and bases (uint32 units)
constexpr int kS0 = 17, kS1 = 21, kS2 = 26;            // res+1
constexpr int kN0 = kS0 * kS0 * kS0;                   // 4913
constexpr int kN1 = kS1 * kS1 * kS1;                   // 9261
constexpr int kN2 = kS2 * kS2 * kS2;                   // 17576
constexpr int kB1 = kN0, kB2 = kN0 + kN1;              // 4913, 14174
constexpr int kNDense = kN0 + kN1 + kN2;               // 31750

// dense-x4 (levels 3-6): group counts (res/2+1)*(res+1)^2
constexpr int kG3 = 17 * 33 * 33;    // 18513
constexpr int kG4 = 21 * 41 * 41;    // 35301
constexpr int kG5 = 26 * 51 * 51;    // 67626
constexpr int kG6 = 33 * 65 * 65;    // 139425
constexpr int kGTot = kG3 + kG4 + kG5 + kG6;           // 260865
// byte offsets of the x4 tables inside ws (after the dense012 region)
constexpr size_t kX4Base3 = 131072;
constexpr size_t kX4Base4 = kX4Base3 + (size_t)kG3 * 16;   // 427280
constexpr size_t kX4Base5 = kX4Base4 + (size_t)kG4 * 16;   // 992096
constexpr size_t kX4Base6 = kX4Base5 + (size_t)kG5 * 16;   // 2074112
// end = 4304912 < 6 MB = packed levels 0-2 region. OK.

// floor(16 * b^i), b = exp(ln(32)/15) in f64 (boundary levels round up).
__constant__ float c_res[kLevels] = {
    16.f, 20.f, 25.f, 32.f, 40.f, 50.f, 64.f, 80.f,
    101.f, 128.f, 161.f, 203.f, 256.f, 322.f, 406.f, 512.f};

__device__ __forceinline__ uint32_t bf16_rtne_hi(float f) {
    uint32_t u = __float_as_uint(f);
    return (u + 0x7FFFu + ((u >> 16) & 1u)) >> 16;
}
__device__ __forceinline__ float bflo(uint32_t e) {
    return __uint_as_float(e << 16);
}
__device__ __forceinline__ float bfhi(uint32_t e) {
    return __uint_as_float(e & 0xFFFF0000u);
}

// ---------------- pass 0: pack tables to bf16x2 ----------------
__global__ __launch_bounds__(256) void pack_tables_kernel(
    const float* __restrict__ tables, uint32_t* __restrict__ packed)
{
    const int i = blockIdx.x * 256 + threadIdx.x;  // 2 entries per thread
    const f32x4 v = reinterpret_cast<const f32x4*>(tables)[i];
    uint2 o;
    o.x = bf16_rtne_hi(v.x) | (bf16_rtne_hi(v.y) << 16);
    o.y = bf16_rtne_hi(v.z) | (bf16_rtne_hi(v.w) << 16);
    reinterpret_cast<uint2*>(packed)[i] = o;
}

// ---------------- pass 0b-1: dense de-hashed tables, levels 0-2 --------
template <int S, int LVL>
__device__ __forceinline__ void build_dense_one(
    int r, const float* __restrict__ tables, uint32_t* __restrict__ dst)
{
    const int bz = r % S;
    const int t = r / S;
    const int by = t % S;
    const int bx = t / S;
    const uint32_t h = ((uint32_t)bx ^ ((uint32_t)by * 2654435761u) ^
                        ((uint32_t)bz * 805459861u)) & kMask;
    const float* src = tables + (((size_t)LVL << 19) + h) * 2;
    dst[r] = bf16_rtne_hi(src[0]) | (bf16_rtne_hi(src[1]) << 16);
}

__global__ __launch_bounds__(256) void build_dense012_kernel(
    const float* __restrict__ tables, uint32_t* __restrict__ dense)
{
    const int idx = blockIdx.x * 256 + threadIdx.x;
    if (idx >= kNDense) return;
    if (idx < kB1)      build_dense_one<kS0, 0>(idx,       tables, dense);
    else if (idx < kB2) build_dense_one<kS1, 1>(idx - kB1, tables, dense + kB1);
    else                build_dense_one<kS2, 2>(idx - kB2, tables, dense + kB2);
}

// ---------------- pass 0b-2: dense-x4 tables, levels 3-6 ----------------
template <int S, int LVL>
__device__ __forceinline__ void build_x4_one(
    int g, const uint32_t* __restrict__ packed, u32x4* __restrict__ dst)
{
    const int bz = g % S;
    const int t = g / S;
    const int by = t % S;
    const int gx = t / S;
    const uint32_t m = ((uint32_t)by * 2654435761u) ^
                       ((uint32_t)bz * 805459861u);
    const uint32_t e = (uint32_t)(gx * 2);
    const uint32_t* tab = packed + ((size_t)LVL << 19);
    u32x4 o;
    o.x = tab[((e + 0) ^ m) & kMask];
    o.y = tab[((e + 1) ^ m) & kMask];
    o.z = tab[((e + 2) ^ m) & kMask];
    o.w = tab[((e + 3) ^ m) & kMask];
    dst[g] = o;
}

__global__ __launch_bounds__(256) void build_x4_kernel(
    const uint32_t* __restrict__ packed, char* __restrict__ ws)
{
    const int g = blockIdx.x * 256 + threadIdx.x;
    if (g >= kGTot) return;
    if (g < kG3)
        build_x4_one<33, 3>(g, packed, (u32x4*)(ws + kX4Base3));
    else if (g < kG3 + kG4)
        build_x4_one<41, 4>(g - kG3, packed, (u32x4*)(ws + kX4Base4));
    else if (g < kG3 + kG4 + kG5)
        build_x4_one<51, 5>(g - kG3 - kG4, packed, (u32x4*)(ws + kX4Base5));
    else
        build_x4_one<65, 6>(g - kG3 - kG4 - kG5, packed, (u32x4*)(ws + kX4Base6));
}

// ---------------- pass A: levels 0-2 via LDS dense tables ----------------
template <int S, int BASE, int LVL>
__device__ __forceinline__ void eval_coarse(
    const uint32_t* __restrict__ lds, float px, float py, float pz, float r,
    uint32_t* __restrict__ lvl_out, int n)
{
    const float tx = px * r, ty = py * r, tz = pz * r;
    const float fx = floorf(tx), fy = floorf(ty), fz = floorf(tz);
    const int bx = (int)fx, by = (int)fy, bz = (int)fz;
    const float rx = tx - fx, ry = ty - fy, rz = tz - fz;
    const int c = BASE + (bx * S + by) * S + bz;
    const uint32_t e000 = lds[c],             e001 = lds[c + 1];
    const uint32_t e010 = lds[c + S],         e011 = lds[c + S + 1];
    const uint32_t e100 = lds[c + S * S],     e101 = lds[c + S * S + 1];
    const uint32_t e110 = lds[c + S * S + S], e111 = lds[c + S * S + S + 1];
    const float wx1 = rx, wx0 = 1.f - rx;
    const float wy1 = ry, wy0 = 1.f - ry;
    const float wz1 = rz, wz0 = 1.f - rz;
    float a0 = 0.f, a1 = 0.f;
    a0 = fmaf(wx0 * wy0 * wz0, bflo(e000), a0);
    a1 = fmaf(wx0 * wy0 * wz0, bfhi(e000), a1);
    a0 = fmaf(wx0 * wy0 * wz1, bflo(e001), a0);
    a1 = fmaf(wx0 * wy0 * wz1, bfhi(e001), a1);
    a0 = fmaf(wx0 * wy1 * wz0, bflo(e010), a0);
    a1 = fmaf(wx0 * wy1 * wz0, bfhi(e010), a1);
    a0 = fmaf(wx0 * wy1 * wz1, bflo(e011), a0);
    a1 = fmaf(wx0 * wy1 * wz1, bfhi(e011), a1);
    a0 = fmaf(wx1 * wy0 * wz0, bflo(e100), a0);
    a1 = fmaf(wx1 * wy0 * wz0, bfhi(e100), a1);
    a0 = fmaf(wx1 * wy0 * wz1, bflo(e101), a0);
    a1 = fmaf(wx1 * wy0 * wz1, bfhi(e101), a1);
    a0 = fmaf(wx1 * wy1 * wz0, bflo(e110), a0);
    a1 = fmaf(wx1 * wy1 * wz0, bfhi(e110), a1);
    a0 = fmaf(wx1 * wy1 * wz1, bflo(e111), a0);
    a1 = fmaf(wx1 * wy1 * wz1, bfhi(e111), a1);
    lvl_out[(size_t)LVL * kPoints + n] =
        bf16_rtne_hi(a0) | (bf16_rtne_hi(a1) << 16);
}

__global__ __launch_bounds__(512) void coarse_kernel(
    const float* __restrict__ x, const uint32_t* __restrict__ dense,
    uint32_t* __restrict__ lvl_out)
{
    __shared__ uint32_t s_tab[kNDense];  // 127000 B
    for (int i = threadIdx.x; i < kNDense; i += 512) s_tab[i] = dense[i];
    __syncthreads();

    const int n0 = blockIdx.x * 2048 + threadIdx.x;
#pragma unroll
    for (int k = 0; k < 4; ++k) {
        const int n = n0 + k * 512;
        const float px = fminf(fmaxf(x[3 * n + 0], 0.0f), 1.0f);
        const float py = fminf(fmaxf(x[3 * n + 1], 0.0f), 1.0f);
        const float pz = fminf(fmaxf(x[3 * n + 2], 0.0f), 1.0f);
        eval_coarse<kS0, 0,   0>(s_tab, px, py, pz, 16.f, lvl_out, n);
        eval_coarse<kS1, kB1, 1>(s_tab, px, py, pz, 20.f, lvl_out, n);
        eval_coarse<kS2, kB2, 2>(s_tab, px, py, pz, 25.f, lvl_out, n);
    }
}

// ---------------- pass B: levels 3-6 via dense-x4 global ----------------
template <int S, int LVL>
__device__ __forceinline__ void eval_mid(
    const u32x4* __restrict__ tab, float px, float py, float pz, float r,
    uint32_t* __restrict__ lvl_out, int n)
{
    const float tx = px * r, ty = py * r, tz = pz * r;
    const float fx = floorf(tx), fy = floorf(ty), fz = floorf(tz);
    const int bx = (int)fx, by = (int)fy, bz = (int)fz;
    const float rx = tx - fx, ry = ty - fy, rz = tz - fz;
    const int gx = bx >> 1;
    const int par = bx & 1;
    const float wx1 = rx, wx0 = 1.f - rx;
    const float wy1 = ry, wy0 = 1.f - ry;
    const float wz1 = rz, wz0 = 1.f - rz;
    float a0 = 0.f, a1 = 0.f;
#pragma unroll
    for (int c = 0; c < 4; ++c) {  // bit1 -> y-corner, bit0 -> z-corner
        const int gidx = (gx * S + (by + ((c >> 1) & 1))) * S + (bz + (c & 1));
        const u32x4 g = tab[gidx];
        const uint32_t lo = par ? g.y : g.x;
        const uint32_t hi = par ? g.z : g.y;
        const float wyz = ((c & 2) ? wy1 : wy0) * ((c & 1) ? wz1 : wz0);
        a0 = fmaf(wyz, fmaf(wx0, bflo(lo), wx1 * bflo(hi)), a0);
        a1 = fmaf(wyz, fmaf(wx0, bfhi(lo), wx1 * bfhi(hi)), a1);
    }
    lvl_out[(size_t)LVL * kPoints + n] =
        bf16_rtne_hi(a0) | (bf16_rtne_hi(a1) << 16);
}

__global__ __launch_bounds__(256) void mid_kernel(
    const float* __restrict__ x, const char* __restrict__ ws,
    uint32_t* __restrict__ lvl_out)
{
    const int b = blockIdx.x;
    const int sub = b >> 11;                 // 0..3 -> level 3..6
    const int chunk = b & 2047;
    const int n0 = chunk * 1024 + threadIdx.x;
#pragma unroll
    for (int k = 0; k < 4; ++k) {
        const int n = n0 + k * 256;
        const float px = fminf(fmaxf(x[3 * n + 0], 0.0f), 1.0f);
        const float py = fminf(fmaxf(x[3 * n + 1], 0.0f), 1.0f);
        const float pz = fminf(fmaxf(x[3 * n + 2], 0.0f), 1.0f);
        if (sub == 0)
            eval_mid<33, 3>((const u32x4*)(ws + kX4Base3), px, py, pz, 32.f, lvl_out, n);
        else if (sub == 1)
            eval_mid<41, 4>((const u32x4*)(ws + kX4Base4), px, py, pz, 40.f, lvl_out, n);
        else if (sub == 2)
            eval_mid<51, 5>((const u32x4*)(ws + kX4Base5), px, py, pz, 50.f, lvl_out, n);
        else
            eval_mid<65, 6>((const u32x4*)(ws + kX4Base6), px, py, pz, 64.f, lvl_out, n);
    }
}

// ------- pass C: levels 7-15 hashed, batched MLP pair+scalar loads ------
__global__ __launch_bounds__(256) void fine_kernel(
    const float* __restrict__ x,
    const uint32_t* __restrict__ packed,
    uint32_t* __restrict__ lvl_out)
{
    const int b = blockIdx.x;
    const int level = 7 + (b >> 11);       // level-at-a-time machine fill
    const int chunk = b & 2047;

    const float r = c_res[level];
    const uint32_t* __restrict__ tab = packed + (size_t)level * kTableSize;
    uint32_t* __restrict__ w = lvl_out + (size_t)level * kPoints;

    const int n0 = chunk * 1024 + threadIdx.x;

    // phase 1: compute all hashes, issue ALL 32 gathers (branch-free).
    // elo = tab[h0] (from the 8B pair at h0&~1), ehi = tab[h1] (scalar).
    // For even bx, h1 = h0^1 lies on the pair's cache line -> MSHR merge.
    float rx[4], ry[4], rz[4];
    uint32_t h0a[4][4];
    uint2 pa[4][4];
    uint32_t sc[4][4];
#pragma unroll
    for (int k = 0; k < 4; ++k) {
        const int n = n0 + k * 256;
        const float px = fminf(fmaxf(x[3 * n + 0], 0.0f), 1.0f);
        const float py = fminf(fmaxf(x[3 * n + 1], 0.0f), 1.0f);
        const float pz = fminf(fmaxf(x[3 * n + 2], 0.0f), 1.0f);
        const float tx = px * r, ty = py * r, tz = pz * r;
        const float fx = floorf(tx), fy = floorf(ty), fz = floorf(tz);
        const int bx = (int)fx, by = (int)fy, bz = (int)fz;
        rx[k] = tx - fx;  ry[k] = ty - fy;  rz[k] = tz - fz;
        const uint32_t hy0 = (uint32_t)by * 2654435761u;
        const uint32_t hy1 = (uint32_t)(by + 1) * 2654435761u;
        const uint32_t hz0 = (uint32_t)bz * 805459861u;
        const uint32_t hz1 = (uint32_t)(bz + 1) * 805459861u;
        const uint32_t bxu = (uint32_t)bx;
        const uint32_t mm[4] = {hy0 ^ hz0, hy0 ^ hz1, hy1 ^ hz0, hy1 ^ hz1};
#pragma unroll
        for (int j = 0; j < 4; ++j) {
            const uint32_t h0 = (bxu ^ mm[j]) & kMask;
            const uint32_t h1 = ((bxu + 1u) ^ mm[j]) & kMask;
            h0a[k][j] = h0;
            pa[k][j] = *reinterpret_cast<const uint2*>(tab + (h0 & ~1u));
            sc[k][j] = tab[h1];
        }
    }

    // phase 2: consume (bit-identical arithmetic to round 6)
#pragma unroll
    for (int k = 0; k < 4; ++k) {
        const float wx1 = rx[k], wx0 = 1.f - rx[k];
        const float wy1 = ry[k], wy0 = 1.f - ry[k];
        const float wz1 = rz[k], wz0 = 1.f - rz[k];
        const float wv[4] = {wy0 * wz0, wy0 * wz1, wy1 * wz0, wy1 * wz1};
        float a0 = 0.f, a1 = 0.f;
#pragma unroll
        for (int j = 0; j < 4; ++j) {
            const uint32_t elo = (h0a[k][j] & 1) ? pa[k][j].y : pa[k][j].x;
            const uint32_t ehi = sc[k][j];
            a0 = fmaf(wv[j], fmaf(wx0, bflo(elo), wx1 * bflo(ehi)), a0);
            a1 = fmaf(wv[j], fmaf(wx0, bfhi(elo), wx1 * bfhi(ehi)), a1);
        }
        const int n = n0 + k * 256;
        w[n] = bf16_rtne_hi(a0) | (bf16_rtne_hi(a1) << 16);
    }
}

// ---------------- pass 2: level-major bf16 -> [N][32] f32 ----------------
__global__ __launch_bounds__(256) void untile_kernel(
    const uint32_t* __restrict__ lvl_out, float* __restrict__ out)
{
    const int n = blockIdx.x * 256 + threadIdx.x;
    float vals[2 * kLevels];
#pragma unroll
    for (int l = 0; l < kLevels; ++l) {
        const uint32_t u = lvl_out[(size_t)l * kPoints + n];
        vals[2 * l + 0] = bflo(u);
        vals[2 * l + 1] = bfhi(u);
    }
    float4* o4 = reinterpret_cast<float4*>(out + (size_t)n * (2 * kLevels));
#pragma unroll
    for (int kq = 0; kq < 8; ++kq) {
        o4[kq] = make_float4(vals[4 * kq + 0], vals[4 * kq + 1],
                             vals[4 * kq + 2], vals[4 * kq + 3]);
    }
}

// ---------------- fallbacks (round-0/round-2 proven paths) --------------
__device__ __forceinline__ void eval_level(
    float px, float py, float pz, float r,
    const uint32_t* __restrict__ tab, float& a0, float& a1)
{
    const float tx = px * r, ty = py * r, tz = pz * r;
    const float fx = floorf(tx), fy = floorf(ty), fz = floorf(tz);
    const int bx = (int)fx, by = (int)fy, bz = (int)fz;
    const float rx = tx - fx, ry = ty - fy, rz = tz - fz;

    const uint32_t hx0 = (uint32_t)bx;
    const uint32_t hx1 = (uint32_t)(bx + 1);
    const uint32_t hy0 = (uint32_t)by * 2654435761u;
    const uint32_t hy1 = (uint32_t)(by + 1) * 2654435761u;
    const uint32_t hz0 = (uint32_t)bz * 805459861u;
    const uint32_t hz1 = (uint32_t)(bz + 1) * 805459861u;

    const float wx1 = rx, wx0 = 1.0f - rx;
    const float wy1 = ry, wy0 = 1.0f - ry;
    const float wz1 = rz, wz0 = 1.0f - rz;

    a0 = 0.0f; a1 = 0.0f;
#pragma unroll
    for (int c = 0; c < 8; ++c) {
        const uint32_t h = (((c & 4) ? hx1 : hx0) ^
                            ((c & 2) ? hy1 : hy0) ^
                            ((c & 1) ? hz1 : hz0)) & kMask;
        const uint32_t e = tab[h];
        const float w = ((c & 4) ? wx1 : wx0) *
                        ((c & 2) ? wy1 : wy0) *
                        ((c & 1) ? wz1 : wz0);
        a0 = fmaf(w, bflo(e), a0);
        a1 = fmaf(w, bfhi(e), a1);
    }
}

__global__ __launch_bounds__(256) void direct_kernel(
    const float* __restrict__ x,
    const float* __restrict__ tables,
    float* __restrict__ out)
{
    const int n = blockIdx.x * 256 + threadIdx.x;
    float px = fminf(fmaxf(x[3 * n + 0], 0.0f), 1.0f);
    float py = fminf(fmaxf(x[3 * n + 1], 0.0f), 1.0f);
    float pz = fminf(fmaxf(x[3 * n + 2], 0.0f), 1.0f);

    const float res_tab[kLevels] = {
        16.f, 20.f, 25.f, 32.f, 40.f, 50.f, 64.f, 80.f,
        101.f, 128.f, 161.f, 203.f, 256.f, 322.f, 406.f, 512.f};

    float acc[2 * kLevels];
#pragma unroll
    for (int l = 0; l < kLevels; ++l) {
        const float r = res_tab[l];
        const float tx = px * r, ty = py * r, tz = pz * r;
        const float fx = floorf(tx), fy = floorf(ty), fz = floorf(tz);
        const int bx = (int)fx, by = (int)fy, bz = (int)fz;
        const float rx = tx - fx, ry = ty - fy, rz = tz - fz;
        const uint32_t hx0 = (uint32_t)bx;
        const uint32_t hx1 = (uint32_t)(bx + 1);
        const uint32_t hy0 = (uint32_t)by * 2654435761u;
        const uint32_t hy1 = (uint32_t)(by + 1) * 2654435761u;
        const uint32_t hz0 = (uint32_t)bz * 805459861u;
        const uint32_t hz1 = (uint32_t)(bz + 1) * 805459861u;
        const float wx1 = rx, wx0 = 1.0f - rx;
        const float wy1 = ry, wy0 = 1.0f - ry;
        const float wz1 = rz, wz0 = 1.0f - rz;
        const float2* __restrict__ tab =
            reinterpret_cast<const float2*>(tables) + (size_t)l * kTableSize;
        float a0 = 0.0f, a1 = 0.0f;
#pragma unroll
        for (int c = 0; c < 8; ++c) {
            const uint32_t h = (((c & 4) ? hx1 : hx0) ^
                                ((c & 2) ? hy1 : hy0) ^
                                ((c & 1) ? hz1 : hz0)) & kMask;
            const float2 e = tab[h];
            const float w = ((c & 4) ? wx1 : wx0) *
                            ((c & 2) ? wy1 : wy0) *
                            ((c & 1) ? wz1 : wz0);
            a0 = fmaf(w, e.x, a0);
            a1 = fmaf(w, e.y, a1);
        }
        acc[2 * l + 0] = a0;
        acc[2 * l + 1] = a1;
    }
    float4* o4 = reinterpret_cast<float4*>(out + (size_t)n * (2 * kLevels));
#pragma unroll
    for (int kq = 0; kq < 8; ++kq) {
        o4[kq] = make_float4(acc[4 * kq + 0], acc[4 * kq + 1],
                             acc[4 * kq + 2], acc[4 * kq + 3]);
    }
}

__global__ __launch_bounds__(256) void direct_packed_kernel(
    const float* __restrict__ x,
    const uint32_t* __restrict__ packed,
    float* __restrict__ out)
{
    const int n = blockIdx.x * 256 + threadIdx.x;
    float px = fminf(fmaxf(x[3 * n + 0], 0.0f), 1.0f);
    float py = fminf(fmaxf(x[3 * n + 1], 0.0f), 1.0f);
    float pz = fminf(fmaxf(x[3 * n + 2], 0.0f), 1.0f);

    const float res_tab[kLevels] = {
        16.f, 20.f, 25.f, 32.f, 40.f, 50.f, 64.f, 80.f,
        101.f, 128.f, 161.f, 203.f, 256.f, 322.f, 406.f, 512.f};

    float acc[2 * kLevels];
#pragma unroll
    for (int l = 0; l < kLevels; ++l) {
        float a0, a1;
        eval_level(px, py, pz, res_tab[l],
                   packed + (size_t)l * kTableSize, a0, a1);
        acc[2 * l + 0] = a0;
        acc[2 * l + 1] = a1;
    }
    float4* o4 = reinterpret_cast<float4*>(out + (size_t)n * (2 * kLevels));
#pragma unroll
    for (int kq = 0; kq < 8; ++kq) {
        o4[kq] = make_float4(acc[4 * kq + 0], acc[4 * kq + 1],
                             acc[4 * kq + 2], acc[4 * kq + 3]);
    }
}

extern "C" void kernel_launch(void* const* d_in, const int* in_sizes, int n_in,
                              void* d_out, int out_size, void* d_ws, size_t ws_size,
                              hipStream_t stream) {
    const float* x = (const float*)d_in[0];       // [2^21, 3] f32
    const float* tables = (const float*)d_in[1];  // [16, 2^19, 2] f32
    float* out = (float*)d_out;                   // [2^21, 32] f32

    if (ws_size >= kPackedBytes + kLvlOutBytes) {
        char* ws = (char*)d_ws;
        uint32_t* packed = (uint32_t*)ws;
        uint32_t* lvl_out = (uint32_t*)(ws + kPackedBytes);
        uint32_t* dense012 = (uint32_t*)ws;  // overlays packed[0..2] (unused)

        hipLaunchKernelGGL(pack_tables_kernel,
                           dim3((kLevels * kTableSize / 2) / 256), dim3(256),
                           0, stream, tables, packed);
        // builds overwrite the packed[0..2] region only; readers of
        // packed[3..6] (build_x4) and packed[7..15] (fine) are untouched.
        hipLaunchKernelGGL(build_dense012_kernel,
                           dim3((kNDense + 255) / 256), dim3(256),
                           0, stream, tables, dense012);
        hipLaunchKernelGGL(build_x4_kernel,
                           dim3((kGTot + 255) / 256), dim3(256),
                           0, stream, packed, ws);
        // pass A: levels 0-2 (LDS), 1024 blocks x 512 thr x 4 pts
        hipLaunchKernelGGL(coarse_kernel, dim3(kPoints / 2048), dim3(512),
                           0, stream, x, dense012, lvl_out);
        // pass B: levels 3-6 (dense-x4), 4 x 2048 blocks
        hipLaunchKernelGGL(mid_kernel, dim3(4 * 2048), dim3(256),
                           0, stream, x, (const char*)ws, lvl_out);
        // pass C: levels 7-15 (hashed, batched), 9 x 2048 blocks
        hipLaunchKernelGGL(fine_kernel, dim3(9 * 2048), dim3(256),
                           0, stream, x, packed, lvl_out);
        // pass 2
        hipLaunchKernelGGL(untile_kernel, dim3(kPoints / 256), dim3(256),
                           0, stream, lvl_out, out);
    } else if (ws_size >= kPackedBytes) {
        uint32_t* packed = (uint32_t*)d_ws;
        hipLaunchKernelGGL(pack_tables_kernel,
                           dim3((kLevels * kTableSize / 2) / 256), dim3(256),
                           0, stream, tables, packed);
        hipLaunchKernelGGL(direct_packed_kernel, dim3(kPoints / 256), dim3(256),
                           0, stream, x, packed, out);
    } else {
        hipLaunchKernelGGL(direct_kernel, dim3(kPoints / 256), dim3(256),
                           0, stream, x, tables, out);
    }
}

// Round 8
// 779.270 us; speedup vs baseline: 1.1046x; 1.1046x over previous
//
#include <hip/hip_runtime.h>
#include <stdint.h>

// HashEmbedder (Instant-NGP multires hash grid), 16 levels, F=2, T=2^19,
// N = 2^21 points.
//
// Round-8 = round-6 + depth-2 software-pipelined fine_kernel.
// Round-7 lesson: uint2 ARRAYS in the two-phase variant went to scratch
// (VGPR=28, WRITE_SIZE 73->679 MB). Fix: branch-free issue/consume with a
// NAMED-FIELD struct (SROA-promotable), explicit 2-point pipeline ->
// ~16 table loads in flight per wave (round 6: ~8, 0.55 lines/cyc,
// latency-bound).
//
//   pass 0 : pack f32 tables -> bf16x2 (4B/entry).
//   pass 0b: dense de-hashed tables for levels 0-2 (124 KB) and dense
//            x4-grouped tables for levels 3-6.
//   pass A : levels 0-2 via LDS-staged dense tables.
//   pass B : levels 3-6 via dense-x4 global tables.
//   pass C : levels 7-15 hashed, level-at-a-time, pair+scalar, 2-deep pipe.
//   pass 2 : transpose level-major bf16x2 -> [N][32] f32.

constexpr int kLevels = 16;
constexpr int kPoints = 1 << 21;
constexpr uint32_t kTableSize = 1u << 19;
constexpr uint32_t kMask = kTableSize - 1u;
constexpr size_t kPackedBytes = (size_t)kLevels * kTableSize * 4;  // 32 MB
constexpr size_t kLvlOutBytes = (size_t)kLevels * kPoints * 4;     // 128 MB

typedef float f32x4 __attribute__((ext_vector_type(4)));
typedef uint32_t u32x4 __attribute__((ext_vector_type(4)));

// dense coarse (levels 0-2): entry counts and bases (uint32 units)
constexpr int kS0 = 17, kS1 = 21, kS2 = 26;            // res+1
constexpr int kN0 = kS0 * kS0 * kS0;                   // 4913
constexpr int kN1 = kS1 * kS1 * kS1;                   // 9261
constexpr int kN2 = kS2 * kS2 * kS2;                   // 17576
constexpr int kB1 = kN0, kB2 = kN0 + kN1;              // 4913, 14174
constexpr int kNDense = kN0 + kN1 + kN2;               // 31750

// dense-x4 (levels 3-6): group counts (res/2+1)*(res+1)^2
constexpr int kG3 = 17 * 33 * 33;    // 18513
constexpr int kG4 = 21 * 41 * 41;    // 35301
constexpr int kG5 = 26 * 51 * 51;    // 67626
constexpr int kG6 = 33 * 65 * 65;    // 139425
constexpr int kGTot = kG3 + kG4 + kG5 + kG6;           // 260865
// byte offsets of the x4 tables inside ws (after the dense012 region)
constexpr size_t kX4Base3 = 131072;
constexpr size_t kX4Base4 = kX4Base3 + (size_t)kG3 * 16;   // 427280
constexpr size_t kX4Base5 = kX4Base4 + (size_t)kG4 * 16;   // 992096
constexpr size_t kX4Base6 = kX4Base5 + (size_t)kG5 * 16;   // 2074112
// end = 4304912 < 6 MB = packed levels 0-2 region. OK.

// floor(16 * b^i), b = exp(ln(32)/15) in f64 (boundary levels round up).
__constant__ float c_res[kLevels] = {
    16.f, 20.f, 25.f, 32.f, 40.f, 50.f, 64.f, 80.f,
    101.f, 128.f, 161.f, 203.f, 256.f, 322.f, 406.f, 512.f};

__device__ __forceinline__ uint32_t bf16_rtne_hi(float f) {
    uint32_t u = __float_as_uint(f);
    return (u + 0x7FFFu + ((u >> 16) & 1u)) >> 16;
}
__device__ __forceinline__ float bflo(uint32_t e) {
    return __uint_as_float(e << 16);
}
__device__ __forceinline__ float bfhi(uint32_t e) {
    return __uint_as_float(e & 0xFFFF0000u);
}

// ---------------- pass 0: pack tables to bf16x2 ----------------
__global__ __launch_bounds__(256) void pack_tables_kernel(
    const float* __restrict__ tables, uint32_t* __restrict__ packed)
{
    const int i = blockIdx.x * 256 + threadIdx.x;  // 2 entries per thread
    const f32x4 v = reinterpret_cast<const f32x4*>(tables)[i];
    uint2 o;
    o.x = bf16_rtne_hi(v.x) | (bf16_rtne_hi(v.y) << 16);
    o.y = bf16_rtne_hi(v.z) | (bf16_rtne_hi(v.w) << 16);
    reinterpret_cast<uint2*>(packed)[i] = o;
}

// ---------------- pass 0b-1: dense de-hashed tables, levels 0-2 --------
template <int S, int LVL>
__device__ __forceinline__ void build_dense_one(
    int r, const float* __restrict__ tables, uint32_t* __restrict__ dst)
{
    const int bz = r % S;
    const int t = r / S;
    const int by = t % S;
    const int bx = t / S;
    const uint32_t h = ((uint32_t)bx ^ ((uint32_t)by * 2654435761u) ^
                        ((uint32_t)bz * 805459861u)) & kMask;
    const float* src = tables + (((size_t)LVL << 19) + h) * 2;
    dst[r] = bf16_rtne_hi(src[0]) | (bf16_rtne_hi(src[1]) << 16);
}

__global__ __launch_bounds__(256) void build_dense012_kernel(
    const float* __restrict__ tables, uint32_t* __restrict__ dense)
{
    const int idx = blockIdx.x * 256 + threadIdx.x;
    if (idx >= kNDense) return;
    if (idx < kB1)      build_dense_one<kS0, 0>(idx,       tables, dense);
    else if (idx < kB2) build_dense_one<kS1, 1>(idx - kB1, tables, dense + kB1);
    else                build_dense_one<kS2, 2>(idx - kB2, tables, dense + kB2);
}

// ---------------- pass 0b-2: dense-x4 tables, levels 3-6 ----------------
template <int S, int LVL>
__device__ __forceinline__ void build_x4_one(
    int g, const uint32_t* __restrict__ packed, u32x4* __restrict__ dst)
{
    const int bz = g % S;
    const int t = g / S;
    const int by = t % S;
    const int gx = t / S;
    const uint32_t m = ((uint32_t)by * 2654435761u) ^
                       ((uint32_t)bz * 805459861u);
    const uint32_t e = (uint32_t)(gx * 2);
    const uint32_t* tab = packed + ((size_t)LVL << 19);
    u32x4 o;
    o.x = tab[((e + 0) ^ m) & kMask];
    o.y = tab[((e + 1) ^ m) & kMask];
    o.z = tab[((e + 2) ^ m) & kMask];
    o.w = tab[((e + 3) ^ m) & kMask];
    dst[g] = o;
}

__global__ __launch_bounds__(256) void build_x4_kernel(
    const uint32_t* __restrict__ packed, char* __restrict__ ws)
{
    const int g = blockIdx.x * 256 + threadIdx.x;
    if (g >= kGTot) return;
    if (g < kG3)
        build_x4_one<33, 3>(g, packed, (u32x4*)(ws + kX4Base3));
    else if (g < kG3 + kG4)
        build_x4_one<41, 4>(g - kG3, packed, (u32x4*)(ws + kX4Base4));
    else if (g < kG3 + kG4 + kG5)
        build_x4_one<51, 5>(g - kG3 - kG4, packed, (u32x4*)(ws + kX4Base5));
    else
        build_x4_one<65, 6>(g - kG3 - kG4 - kG5, packed, (u32x4*)(ws + kX4Base6));
}

// ---------------- pass A: levels 0-2 via LDS dense tables ----------------
template <int S, int BASE, int LVL>
__device__ __forceinline__ void eval_coarse(
    const uint32_t* __restrict__ lds, float px, float py, float pz, float r,
    uint32_t* __restrict__ lvl_out, int n)
{
    const float tx = px * r, ty = py * r, tz = pz * r;
    const float fx = floorf(tx), fy = floorf(ty), fz = floorf(tz);
    const int bx = (int)fx, by = (int)fy, bz = (int)fz;
    const float rx = tx - fx, ry = ty - fy, rz = tz - fz;
    const int c = BASE + (bx * S + by) * S + bz;
    const uint32_t e000 = lds[c],             e001 = lds[c + 1];
    const uint32_t e010 = lds[c + S],         e011 = lds[c + S + 1];
    const uint32_t e100 = lds[c + S * S],     e101 = lds[c + S * S + 1];
    const uint32_t e110 = lds[c + S * S + S], e111 = lds[c + S * S + S + 1];
    const float wx1 = rx, wx0 = 1.f - rx;
    const float wy1 = ry, wy0 = 1.f - ry;
    const float wz1 = rz, wz0 = 1.f - rz;
    float a0 = 0.f, a1 = 0.f;
    a0 = fmaf(wx0 * wy0 * wz0, bflo(e000), a0);
    a1 = fmaf(wx0 * wy0 * wz0, bfhi(e000), a1);
    a0 = fmaf(wx0 * wy0 * wz1, bflo(e001), a0);
    a1 = fmaf(wx0 * wy0 * wz1, bfhi(e001), a1);
    a0 = fmaf(wx0 * wy1 * wz0, bflo(e010), a0);
    a1 = fmaf(wx0 * wy1 * wz0, bfhi(e010), a1);
    a0 = fmaf(wx0 * wy1 * wz1, bflo(e011), a0);
    a1 = fmaf(wx0 * wy1 * wz1, bfhi(e011), a1);
    a0 = fmaf(wx1 * wy0 * wz0, bflo(e100), a0);
    a1 = fmaf(wx1 * wy0 * wz0, bfhi(e100), a1);
    a0 = fmaf(wx1 * wy0 * wz1, bflo(e101), a0);
    a1 = fmaf(wx1 * wy0 * wz1, bfhi(e101), a1);
    a0 = fmaf(wx1 * wy1 * wz0, bflo(e110), a0);
    a1 = fmaf(wx1 * wy1 * wz0, bfhi(e110), a1);
    a0 = fmaf(wx1 * wy1 * wz1, bflo(e111), a0);
    a1 = fmaf(wx1 * wy1 * wz1, bfhi(e111), a1);
    lvl_out[(size_t)LVL * kPoints + n] =
        bf16_rtne_hi(a0) | (bf16_rtne_hi(a1) << 16);
}

__global__ __launch_bounds__(512) void coarse_kernel(
    const float* __restrict__ x, const uint32_t* __restrict__ dense,
    uint32_t* __restrict__ lvl_out)
{
    __shared__ uint32_t s_tab[kNDense];  // 127000 B
    for (int i = threadIdx.x; i < kNDense; i += 512) s_tab[i] = dense[i];
    __syncthreads();

    const int n0 = blockIdx.x * 2048 + threadIdx.x;
#pragma unroll
    for (int k = 0; k < 4; ++k) {
        const int n = n0 + k * 512;
        const float px = fminf(fmaxf(x[3 * n + 0], 0.0f), 1.0f);
        const float py = fminf(fmaxf(x[3 * n + 1], 0.0f), 1.0f);
        const float pz = fminf(fmaxf(x[3 * n + 2], 0.0f), 1.0f);
        eval_coarse<kS0, 0,   0>(s_tab, px, py, pz, 16.f, lvl_out, n);
        eval_coarse<kS1, kB1, 1>(s_tab, px, py, pz, 20.f, lvl_out, n);
        eval_coarse<kS2, kB2, 2>(s_tab, px, py, pz, 25.f, lvl_out, n);
    }
}

// ---------------- pass B: levels 3-6 via dense-x4 global ----------------
template <int S, int LVL>
__device__ __forceinline__ void eval_mid(
    const u32x4* __restrict__ tab, float px, float py, float pz, float r,
    uint32_t* __restrict__ lvl_out, int n)
{
    const float tx = px * r, ty = py * r, tz = pz * r;
    const float fx = floorf(tx), fy = floorf(ty), fz = floorf(tz);
    const int bx = (int)fx, by = (int)fy, bz = (int)fz;
    const float rx = tx - fx, ry = ty - fy, rz = tz - fz;
    const int gx = bx >> 1;
    const int par = bx & 1;
    const float wx1 = rx, wx0 = 1.f - rx;
    const float wy1 = ry, wy0 = 1.f - ry;
    const float wz1 = rz, wz0 = 1.f - rz;
    float a0 = 0.f, a1 = 0.f;
#pragma unroll
    for (int c = 0; c < 4; ++c) {  // bit1 -> y-corner, bit0 -> z-corner
        const int gidx = (gx * S + (by + ((c >> 1) & 1))) * S + (bz + (c & 1));
        const u32x4 g = tab[gidx];
        const uint32_t lo = par ? g.y : g.x;
        const uint32_t hi = par ? g.z : g.y;
        const float wyz = ((c & 2) ? wy1 : wy0) * ((c & 1) ? wz1 : wz0);
        a0 = fmaf(wyz, fmaf(wx0, bflo(lo), wx1 * bflo(hi)), a0);
        a1 = fmaf(wyz, fmaf(wx0, bfhi(lo), wx1 * bfhi(hi)), a1);
    }
    lvl_out[(size_t)LVL * kPoints + n] =
        bf16_rtne_hi(a0) | (bf16_rtne_hi(a1) << 16);
}

__global__ __launch_bounds__(256) void mid_kernel(
    const float* __restrict__ x, const char* __restrict__ ws,
    uint32_t* __restrict__ lvl_out)
{
    const int b = blockIdx.x;
    const int sub = b >> 11;                 // 0..3 -> level 3..6
    const int chunk = b & 2047;
    const int n0 = chunk * 1024 + threadIdx.x;
#pragma unroll
    for (int k = 0; k < 4; ++k) {
        const int n = n0 + k * 256;
        const float px = fminf(fmaxf(x[3 * n + 0], 0.0f), 1.0f);
        const float py = fminf(fmaxf(x[3 * n + 1], 0.0f), 1.0f);
        const float pz = fminf(fmaxf(x[3 * n + 2], 0.0f), 1.0f);
        if (sub == 0)
            eval_mid<33, 3>((const u32x4*)(ws + kX4Base3), px, py, pz, 32.f, lvl_out, n);
        else if (sub == 1)
            eval_mid<41, 4>((const u32x4*)(ws + kX4Base4), px, py, pz, 40.f, lvl_out, n);
        else if (sub == 2)
            eval_mid<51, 5>((const u32x4*)(ws + kX4Base5), px, py, pz, 50.f, lvl_out, n);
        else
            eval_mid<65, 6>((const u32x4*)(ws + kX4Base6), px, py, pz, 64.f, lvl_out, n);
    }
}

// ------- pass C: levels 7-15 hashed, 2-deep pipelined pair+scalar -------
// Named-field struct (SROA-promotable; round-7's arrays spilled to scratch).
struct PtSt {
    float rx, ry, rz;
    uint32_t q0, q1, q2, q3;   // low-corner hashes (bit0 = pair selector)
    uint2 p0, p1, p2, p3;      // 8B pair loads at q&~1
    uint32_t s0, s1, s2, s3;   // 4B scalar loads at high-corner hash
};

__device__ __forceinline__ void issue_pt(
    PtSt& st, const float* __restrict__ x, int n, float r,
    const uint32_t* __restrict__ tab)
{
    const float px = fminf(fmaxf(x[3 * n + 0], 0.f), 1.f);
    const float py = fminf(fmaxf(x[3 * n + 1], 0.f), 1.f);
    const float pz = fminf(fmaxf(x[3 * n + 2], 0.f), 1.f);
    const float tx = px * r, ty = py * r, tz = pz * r;
    const float fx = floorf(tx), fy = floorf(ty), fz = floorf(tz);
    const int bx = (int)fx, by = (int)fy, bz = (int)fz;
    st.rx = tx - fx;  st.ry = ty - fy;  st.rz = tz - fz;
    const uint32_t hy0 = (uint32_t)by * 2654435761u;
    const uint32_t hy1 = (uint32_t)(by + 1) * 2654435761u;
    const uint32_t hz0 = (uint32_t)bz * 805459861u;
    const uint32_t hz1 = (uint32_t)(bz + 1) * 805459861u;
    const uint32_t bxu = (uint32_t)bx, bx1 = bxu + 1u;
    const uint32_t m0 = hy0 ^ hz0, m1 = hy0 ^ hz1;
    const uint32_t m2 = hy1 ^ hz0, m3 = hy1 ^ hz1;
    st.q0 = (bxu ^ m0) & kMask;
    st.q1 = (bxu ^ m1) & kMask;
    st.q2 = (bxu ^ m2) & kMask;
    st.q3 = (bxu ^ m3) & kMask;
    st.p0 = *reinterpret_cast<const uint2*>(tab + (st.q0 & ~1u));
    st.p1 = *reinterpret_cast<const uint2*>(tab + (st.q1 & ~1u));
    st.p2 = *reinterpret_cast<const uint2*>(tab + (st.q2 & ~1u));
    st.p3 = *reinterpret_cast<const uint2*>(tab + (st.q3 & ~1u));
    st.s0 = tab[(bx1 ^ m0) & kMask];
    st.s1 = tab[(bx1 ^ m1) & kMask];
    st.s2 = tab[(bx1 ^ m2) & kMask];
    st.s3 = tab[(bx1 ^ m3) & kMask];
}

__device__ __forceinline__ void consume_pt(
    const PtSt& st, uint32_t* __restrict__ w, int n)
{
    const float wx1 = st.rx, wx0 = 1.f - st.rx;
    const float wy1 = st.ry, wy0 = 1.f - st.ry;
    const float wz1 = st.rz, wz0 = 1.f - st.rz;
    const float w0 = wy0 * wz0, w1 = wy0 * wz1;
    const float w2 = wy1 * wz0, w3 = wy1 * wz1;
    const uint32_t e0 = (st.q0 & 1) ? st.p0.y : st.p0.x;
    const uint32_t e1 = (st.q1 & 1) ? st.p1.y : st.p1.x;
    const uint32_t e2 = (st.q2 & 1) ? st.p2.y : st.p2.x;
    const uint32_t e3 = (st.q3 & 1) ? st.p3.y : st.p3.x;
    float a0 = 0.f, a1 = 0.f;
    a0 = fmaf(w0, fmaf(wx0, bflo(e0), wx1 * bflo(st.s0)), a0);
    a1 = fmaf(w0, fmaf(wx0, bfhi(e0), wx1 * bfhi(st.s0)), a1);
    a0 = fmaf(w1, fmaf(wx0, bflo(e1), wx1 * bflo(st.s1)), a0);
    a1 = fmaf(w1, fmaf(wx0, bfhi(e1), wx1 * bfhi(st.s1)), a1);
    a0 = fmaf(w2, fmaf(wx0, bflo(e2), wx1 * bflo(st.s2)), a0);
    a1 = fmaf(w2, fmaf(wx0, bfhi(e2), wx1 * bfhi(st.s2)), a1);
    a0 = fmaf(w3, fmaf(wx0, bflo(e3), wx1 * bflo(st.s3)), a0);
    a1 = fmaf(w3, fmaf(wx0, bfhi(e3), wx1 * bfhi(st.s3)), a1);
    w[n] = bf16_rtne_hi(a0) | (bf16_rtne_hi(a1) << 16);
}

__global__ __launch_bounds__(256) void fine_kernel(
    const float* __restrict__ x,
    const uint32_t* __restrict__ packed,
    uint32_t* __restrict__ lvl_out)
{
    const int b = blockIdx.x;
    const int level = 7 + (b >> 11);       // level-at-a-time machine fill
    const int chunk = b & 2047;

    const float r = c_res[level];
    const uint32_t* __restrict__ tab = packed + (size_t)level * kTableSize;
    uint32_t* __restrict__ w = lvl_out + (size_t)level * kPoints;

    const int n0 = chunk * 1024 + threadIdx.x;

    PtSt A, B;
    issue_pt(A, x, n0 + 0 * 256, r, tab);
    issue_pt(B, x, n0 + 1 * 256, r, tab);
    consume_pt(A, w, n0 + 0 * 256);
    issue_pt(A, x, n0 + 2 * 256, r, tab);
    consume_pt(B, w, n0 + 1 * 256);
    issue_pt(B, x, n0 + 3 * 256, r, tab);
    consume_pt(A, w, n0 + 2 * 256);
    consume_pt(B, w, n0 + 3 * 256);
}

// ---------------- pass 2: level-major bf16 -> [N][32] f32 ----------------
__global__ __launch_bounds__(256) void untile_kernel(
    const uint32_t* __restrict__ lvl_out, float* __restrict__ out)
{
    const int n = blockIdx.x * 256 + threadIdx.x;
    float vals[2 * kLevels];
#pragma unroll
    for (int l = 0; l < kLevels; ++l) {
        const uint32_t u = lvl_out[(size_t)l * kPoints + n];
        vals[2 * l + 0] = bflo(u);
        vals[2 * l + 1] = bfhi(u);
    }
    float4* o4 = reinterpret_cast<float4*>(out + (size_t)n * (2 * kLevels));
#pragma unroll
    for (int kq = 0; kq < 8; ++kq) {
        o4[kq] = make_float4(vals[4 * kq + 0], vals[4 * kq + 1],
                             vals[4 * kq + 2], vals[4 * kq + 3]);
    }
}

// ---------------- fallbacks (round-0/round-2 proven paths) --------------
__device__ __forceinline__ void eval_level(
    float px, float py, float pz, float r,
    const uint32_t* __restrict__ tab, float& a0, float& a1)
{
    const float tx = px * r, ty = py * r, tz = pz * r;
    const float fx = floorf(tx), fy = floorf(ty), fz = floorf(tz);
    const int bx = (int)fx, by = (int)fy, bz = (int)fz;
    const float rx = tx - fx, ry = ty - fy, rz = tz - fz;

    const uint32_t hx0 = (uint32_t)bx;
    const uint32_t hx1 = (uint32_t)(bx + 1);
    const uint32_t hy0 = (uint32_t)by * 2654435761u;
    const uint32_t hy1 = (uint32_t)(by + 1) * 2654435761u;
    const uint32_t hz0 = (uint32_t)bz * 805459861u;
    const uint32_t hz1 = (uint32_t)(bz + 1) * 805459861u;

    const float wx1 = rx, wx0 = 1.0f - rx;
    const float wy1 = ry, wy0 = 1.0f - ry;
    const float wz1 = rz, wz0 = 1.0f - rz;

    a0 = 0.0f; a1 = 0.0f;
#pragma unroll
    for (int c = 0; c < 8; ++c) {
        const uint32_t h = (((c & 4) ? hx1 : hx0) ^
                            ((c & 2) ? hy1 : hy0) ^
                            ((c & 1) ? hz1 : hz0)) & kMask;
        const uint32_t e = tab[h];
        const float w = ((c & 4) ? wx1 : wx0) *
                        ((c & 2) ? wy1 : wy0) *
                        ((c & 1) ? wz1 : wz0);
        a0 = fmaf(w, bflo(e), a0);
        a1 = fmaf(w, bfhi(e), a1);
    }
}

__global__ __launch_bounds__(256) void direct_kernel(
    const float* __restrict__ x,
    const float* __restrict__ tables,
    float* __restrict__ out)
{
    const int n = blockIdx.x * 256 + threadIdx.x;
    float px = fminf(fmaxf(x[3 * n + 0], 0.0f), 1.0f);
    float py = fminf(fmaxf(x[3 * n + 1], 0.0f), 1.0f);
    float pz = fminf(fmaxf(x[3 * n + 2], 0.0f), 1.0f);

    const float res_tab[kLevels] = {
        16.f, 20.f, 25.f, 32.f, 40.f, 50.f, 64.f, 80.f,
        101.f, 128.f, 161.f, 203.f, 256.f, 322.f, 406.f, 512.f};

    float acc[2 * kLevels];
#pragma unroll
    for (int l = 0; l < kLevels; ++l) {
        const float r = res_tab[l];
        const float tx = px * r, ty = py * r, tz = pz * r;
        const float fx = floorf(tx), fy = floorf(ty), fz = floorf(tz);
        const int bx = (int)fx, by = (int)fy, bz = (int)fz;
        const float rx = tx - fx, ry = ty - fy, rz = tz - fz;
        const uint32_t hx0 = (uint32_t)bx;
        const uint32_t hx1 = (uint32_t)(bx + 1);
        const uint32_t hy0 = (uint32_t)by * 2654435761u;
        const uint32_t hy1 = (uint32_t)(by + 1) * 2654435761u;
        const uint32_t hz0 = (uint32_t)bz * 805459861u;
        const uint32_t hz1 = (uint32_t)(bz + 1) * 805459861u;
        const float wx1 = rx, wx0 = 1.0f - rx;
        const float wy1 = ry, wy0 = 1.0f - ry;
        const float wz1 = rz, wz0 = 1.0f - rz;
        const float2* __restrict__ tab =
            reinterpret_cast<const float2*>(tables) + (size_t)l * kTableSize;
        float a0 = 0.0f, a1 = 0.0f;
#pragma unroll
        for (int c = 0; c < 8; ++c) {
            const uint32_t h = (((c & 4) ? hx1 : hx0) ^
                                ((c & 2) ? hy1 : hy0) ^
                                ((c & 1) ? hz1 : hz0)) & kMask;
            const float2 e = tab[h];
            const float w = ((c & 4) ? wx1 : wx0) *
                            ((c & 2) ? wy1 : wy0) *
                            ((c & 1) ? wz1 : wz0);
            a0 = fmaf(w, e.x, a0);
            a1 = fmaf(w, e.y, a1);
        }
        acc[2 * l + 0] = a0;
        acc[2 * l + 1] = a1;
    }
    float4* o4 = reinterpret_cast<float4*>(out + (size_t)n * (2 * kLevels));
#pragma unroll
    for (int kq = 0; kq < 8; ++kq) {
        o4[kq] = make_float4(acc[4 * kq + 0], acc[4 * kq + 1],
                             acc[4 * kq + 2], acc[4 * kq + 3]);
    }
}

__global__ __launch_bounds__(256) void direct_packed_kernel(
    const float* __restrict__ x,
    const uint32_t* __restrict__ packed,
    float* __restrict__ out)
{
    const int n = blockIdx.x * 256 + threadIdx.x;
    float px = fminf(fmaxf(x[3 * n + 0], 0.0f), 1.0f);
    float py = fminf(fmaxf(x[3 * n + 1], 0.0f), 1.0f);
    float pz = fminf(fmaxf(x[3 * n + 2], 0.0f), 1.0f);

    const float res_tab[kLevels] = {
        16.f, 20.f, 25.f, 32.f, 40.f, 50.f, 64.f, 80.f,
        101.f, 128.f, 161.f, 203.f, 256.f, 322.f, 406.f, 512.f};

    float acc[2 * kLevels];
#pragma unroll
    for (int l = 0; l < kLevels; ++l) {
        float a0, a1;
        eval_level(px, py, pz, res_tab[l],
                   packed + (size_t)l * kTableSize, a0, a1);
        acc[2 * l + 0] = a0;
        acc[2 * l + 1] = a1;
    }
    float4* o4 = reinterpret_cast<float4*>(out + (size_t)n * (2 * kLevels));
#pragma unroll
    for (int kq = 0; kq < 8; ++kq) {
        o4[kq] = make_float4(acc[4 * kq + 0], acc[4 * kq + 1],
                             acc[4 * kq + 2], acc[4 * kq + 3]);
    }
}

extern "C" void kernel_launch(void* const* d_in, const int* in_sizes, int n_in,
                              void* d_out, int out_size, void* d_ws, size_t ws_size,
                              hipStream_t stream) {
    const float* x = (const float*)d_in[0];       // [2^21, 3] f32
    const float* tables = (const float*)d_in[1];  // [16, 2^19, 2] f32
    float* out = (float*)d_out;                   // [2^21, 32] f32

    if (ws_size >= kPackedBytes + kLvlOutBytes) {
        char* ws = (char*)d_ws;
        uint32_t* packed = (uint32_t*)ws;
        uint32_t* lvl_out = (uint32_t*)(ws + kPackedBytes);
        uint32_t* dense012 = (uint32_t*)ws;  // overlays packed[0..2] (unused)

        hipLaunchKernelGGL(pack_tables_kernel,
                           dim3((kLevels * kTableSize / 2) / 256), dim3(256),
                           0, stream, tables, packed);
        // builds overwrite the packed[0..2] region only; readers of
        // packed[3..6] (build_x4) and packed[7..15] (fine) are untouched.
        hipLaunchKernelGGL(build_dense012_kernel,
                           dim3((kNDense + 255) / 256), dim3(256),
                           0, stream, tables, dense012);
        hipLaunchKernelGGL(build_x4_kernel,
                           dim3((kGTot + 255) / 256), dim3(256),
                           0, stream, packed, ws);
        // pass A: levels 0-2 (LDS), 1024 blocks x 512 thr x 4 pts
        hipLaunchKernelGGL(coarse_kernel, dim3(kPoints / 2048), dim3(512),
                           0, stream, x, dense012, lvl_out);
        // pass B: levels 3-6 (dense-x4), 4 x 2048 blocks
        hipLaunchKernelGGL(mid_kernel, dim3(4 * 2048), dim3(256),
                           0, stream, x, (const char*)ws, lvl_out);
        // pass C: levels 7-15 (hashed, 2-deep pipelined), 9 x 2048 blocks
        hipLaunchKernelGGL(fine_kernel, dim3(9 * 2048), dim3(256),
                           0, stream, x, packed, lvl_out);
        // pass 2
        hipLaunchKernelGGL(untile_kernel, dim3(kPoints / 256), dim3(256),
                           0, stream, lvl_out, out);
    } else if (ws_size >= kPackedBytes) {
        uint32_t* packed = (uint32_t*)d_ws;
        hipLaunchKernelGGL(pack_tables_kernel,
                           dim3((kLevels * kTableSize / 2) / 256), dim3(256),
                           0, stream, tables, packed);
        hipLaunchKernelGGL(direct_packed_kernel, dim3(kPoints / 256), dim3(256),
                           0, stream, x, packed, out);
    } else {
        hipLaunchKernelGGL(direct_kernel, dim3(kPoints / 256), dim3(256),
                           0, stream, x, tables, out);
    }
}

// Round 9
// 572.254 us; speedup vs baseline: 1.5042x; 1.3618x over previous
//
#include <hip/hip_runtime.h>
#include <stdint.h>

// HashEmbedder (Instant-NGP multires hash grid), 16 levels, F=2, T=2^19,
// N = 2^21 points.
//
// Round-9 = round-6 fine structure (branchy even-bx pairing, 6 line-
// lookups/pt) + 2-deep software pipeline PINNED with sched_barrier(0).
// Round-8 lesson: SROA worked (no spill) but the scheduler sank loads to
// uses (VGPR=28) -> serialized. sched_barrier(0) walls at phase
// boundaries stop the sinking. Odd-bx arm writes its scalars into the
// pair slots with sel=0 so consume is branch-free; arithmetic
// bit-identical to rounds 5-8.
//
//   pass 0 : pack f32 tables -> bf16x2 (4B/entry).
//   pass 0b: dense de-hashed tables for levels 0-2 (124 KB) and dense
//            x4-grouped tables for levels 3-6.
//   pass A : levels 0-2 via LDS-staged dense tables.
//   pass B : levels 3-6 via dense-x4 global tables.
//   pass C : levels 7-15 hashed, level-at-a-time, paired, 2-deep pipe.
//   pass 2 : transpose level-major bf16x2 -> [N][32] f32.

constexpr int kLevels = 16;
constexpr int kPoints = 1 << 21;
constexpr uint32_t kTableSize = 1u << 19;
constexpr uint32_t kMask = kTableSize - 1u;
constexpr size_t kPackedBytes = (size_t)kLevels * kTableSize * 4;  // 32 MB
constexpr size_t kLvlOutBytes = (size_t)kLevels * kPoints * 4;     // 128 MB

typedef float f32x4 __attribute__((ext_vector_type(4)));
typedef uint32_t u32x4 __attribute__((ext_vector_type(4)));

// dense coarse (levels 0-2): entry counts and bases (uint32 units)
constexpr int kS0 = 17, kS1 = 21, kS2 = 26;            // res+1
constexpr int kN0 = kS0 * kS0 * kS0;                   // 4913
constexpr int kN1 = kS1 * kS1 * kS1;                   // 9261
constexpr int kN2 = kS2 * kS2 * kS2;                   // 17576
constexpr int kB1 = kN0, kB2 = kN0 + kN1;              // 4913, 14174
constexpr int kNDense = kN0 + kN1 + kN2;               // 31750

// dense-x4 (levels 3-6): group counts (res/2+1)*(res+1)^2
constexpr int kG3 = 17 * 33 * 33;    // 18513
constexpr int kG4 = 21 * 41 * 41;    // 35301
constexpr int kG5 = 26 * 51 * 51;    // 67626
constexpr int kG6 = 33 * 65 * 65;    // 139425
constexpr int kGTot = kG3 + kG4 + kG5 + kG6;           // 260865
// byte offsets of the x4 tables inside ws (after the dense012 region)
constexpr size_t kX4Base3 = 131072;
constexpr size_t kX4Base4 = kX4Base3 + (size_t)kG3 * 16;   // 427280
constexpr size_t kX4Base5 = kX4Base4 + (size_t)kG4 * 16;   // 992096
constexpr size_t kX4Base6 = kX4Base5 + (size_t)kG5 * 16;   // 2074112
// end = 4304912 < 6 MB = packed levels 0-2 region. OK.

// floor(16 * b^i), b = exp(ln(32)/15) in f64 (boundary levels round up).
__constant__ float c_res[kLevels] = {
    16.f, 20.f, 25.f, 32.f, 40.f, 50.f, 64.f, 80.f,
    101.f, 128.f, 161.f, 203.f, 256.f, 322.f, 406.f, 512.f};

__device__ __forceinline__ uint32_t bf16_rtne_hi(float f) {
    uint32_t u = __float_as_uint(f);
    return (u + 0x7FFFu + ((u >> 16) & 1u)) >> 16;
}
__device__ __forceinline__ float bflo(uint32_t e) {
    return __uint_as_float(e << 16);
}
__device__ __forceinline__ float bfhi(uint32_t e) {
    return __uint_as_float(e & 0xFFFF0000u);
}

// ---------------- pass 0: pack tables to bf16x2 ----------------
__global__ __launch_bounds__(256) void pack_tables_kernel(
    const float* __restrict__ tables, uint32_t* __restrict__ packed)
{
    const int i = blockIdx.x * 256 + threadIdx.x;  // 2 entries per thread
    const f32x4 v = reinterpret_cast<const f32x4*>(tables)[i];
    uint2 o;
    o.x = bf16_rtne_hi(v.x) | (bf16_rtne_hi(v.y) << 16);
    o.y = bf16_rtne_hi(v.z) | (bf16_rtne_hi(v.w) << 16);
    reinterpret_cast<uint2*>(packed)[i] = o;
}

// ---------------- pass 0b-1: dense de-hashed tables, levels 0-2 --------
template <int S, int LVL>
__device__ __forceinline__ void build_dense_one(
    int r, const float* __restrict__ tables, uint32_t* __restrict__ dst)
{
    const int bz = r % S;
    const int t = r / S;
    const int by = t % S;
    const int bx = t / S;
    const uint32_t h = ((uint32_t)bx ^ ((uint32_t)by * 2654435761u) ^
                        ((uint32_t)bz * 805459861u)) & kMask;
    const float* src = tables + (((size_t)LVL << 19) + h) * 2;
    dst[r] = bf16_rtne_hi(src[0]) | (bf16_rtne_hi(src[1]) << 16);
}

__global__ __launch_bounds__(256) void build_dense012_kernel(
    const float* __restrict__ tables, uint32_t* __restrict__ dense)
{
    const int idx = blockIdx.x * 256 + threadIdx.x;
    if (idx >= kNDense) return;
    if (idx < kB1)      build_dense_one<kS0, 0>(idx,       tables, dense);
    else if (idx < kB2) build_dense_one<kS1, 1>(idx - kB1, tables, dense + kB1);
    else                build_dense_one<kS2, 2>(idx - kB2, tables, dense + kB2);
}

// ---------------- pass 0b-2: dense-x4 tables, levels 3-6 ----------------
template <int S, int LVL>
__device__ __forceinline__ void build_x4_one(
    int g, const uint32_t* __restrict__ packed, u32x4* __restrict__ dst)
{
    const int bz = g % S;
    const int t = g / S;
    const int by = t % S;
    const int gx = t / S;
    const uint32_t m = ((uint32_t)by * 2654435761u) ^
                       ((uint32_t)bz * 805459861u);
    const uint32_t e = (uint32_t)(gx * 2);
    const uint32_t* tab = packed + ((size_t)LVL << 19);
    u32x4 o;
    o.x = tab[((e + 0) ^ m) & kMask];
    o.y = tab[((e + 1) ^ m) & kMask];
    o.z = tab[((e + 2) ^ m) & kMask];
    o.w = tab[((e + 3) ^ m) & kMask];
    dst[g] = o;
}

__global__ __launch_bounds__(256) void build_x4_kernel(
    const uint32_t* __restrict__ packed, char* __restrict__ ws)
{
    const int g = blockIdx.x * 256 + threadIdx.x;
    if (g >= kGTot) return;
    if (g < kG3)
        build_x4_one<33, 3>(g, packed, (u32x4*)(ws + kX4Base3));
    else if (g < kG3 + kG4)
        build_x4_one<41, 4>(g - kG3, packed, (u32x4*)(ws + kX4Base4));
    else if (g < kG3 + kG4 + kG5)
        build_x4_one<51, 5>(g - kG3 - kG4, packed, (u32x4*)(ws + kX4Base5));
    else
        build_x4_one<65, 6>(g - kG3 - kG4 - kG5, packed, (u32x4*)(ws + kX4Base6));
}

// ---------------- pass A: levels 0-2 via LDS dense tables ----------------
template <int S, int BASE, int LVL>
__device__ __forceinline__ void eval_coarse(
    const uint32_t* __restrict__ lds, float px, float py, float pz, float r,
    uint32_t* __restrict__ lvl_out, int n)
{
    const float tx = px * r, ty = py * r, tz = pz * r;
    const float fx = floorf(tx), fy = floorf(ty), fz = floorf(tz);
    const int bx = (int)fx, by = (int)fy, bz = (int)fz;
    const float rx = tx - fx, ry = ty - fy, rz = tz - fz;
    const int c = BASE + (bx * S + by) * S + bz;
    const uint32_t e000 = lds[c],             e001 = lds[c + 1];
    const uint32_t e010 = lds[c + S],         e011 = lds[c + S + 1];
    const uint32_t e100 = lds[c + S * S],     e101 = lds[c + S * S + 1];
    const uint32_t e110 = lds[c + S * S + S], e111 = lds[c + S * S + S + 1];
    const float wx1 = rx, wx0 = 1.f - rx;
    const float wy1 = ry, wy0 = 1.f - ry;
    const float wz1 = rz, wz0 = 1.f - rz;
    float a0 = 0.f, a1 = 0.f;
    a0 = fmaf(wx0 * wy0 * wz0, bflo(e000), a0);
    a1 = fmaf(wx0 * wy0 * wz0, bfhi(e000), a1);
    a0 = fmaf(wx0 * wy0 * wz1, bflo(e001), a0);
    a1 = fmaf(wx0 * wy0 * wz1, bfhi(e001), a1);
    a0 = fmaf(wx0 * wy1 * wz0, bflo(e010), a0);
    a1 = fmaf(wx0 * wy1 * wz0, bfhi(e010), a1);
    a0 = fmaf(wx0 * wy1 * wz1, bflo(e011), a0);
    a1 = fmaf(wx0 * wy1 * wz1, bfhi(e011), a1);
    a0 = fmaf(wx1 * wy0 * wz0, bflo(e100), a0);
    a1 = fmaf(wx1 * wy0 * wz0, bfhi(e100), a1);
    a0 = fmaf(wx1 * wy0 * wz1, bflo(e101), a0);
    a1 = fmaf(wx1 * wy0 * wz1, bfhi(e101), a1);
    a0 = fmaf(wx1 * wy1 * wz0, bflo(e110), a0);
    a1 = fmaf(wx1 * wy1 * wz0, bfhi(e110), a1);
    a0 = fmaf(wx1 * wy1 * wz1, bflo(e111), a0);
    a1 = fmaf(wx1 * wy1 * wz1, bfhi(e111), a1);
    lvl_out[(size_t)LVL * kPoints + n] =
        bf16_rtne_hi(a0) | (bf16_rtne_hi(a1) << 16);
}

__global__ __launch_bounds__(512) void coarse_kernel(
    const float* __restrict__ x, const uint32_t* __restrict__ dense,
    uint32_t* __restrict__ lvl_out)
{
    __shared__ uint32_t s_tab[kNDense];  // 127000 B
    for (int i = threadIdx.x; i < kNDense; i += 512) s_tab[i] = dense[i];
    __syncthreads();

    const int n0 = blockIdx.x * 2048 + threadIdx.x;
#pragma unroll
    for (int k = 0; k < 4; ++k) {
        const int n = n0 + k * 512;
        const float px = fminf(fmaxf(x[3 * n + 0], 0.0f), 1.0f);
        const float py = fminf(fmaxf(x[3 * n + 1], 0.0f), 1.0f);
        const float pz = fminf(fmaxf(x[3 * n + 2], 0.0f), 1.0f);
        eval_coarse<kS0, 0,   0>(s_tab, px, py, pz, 16.f, lvl_out, n);
        eval_coarse<kS1, kB1, 1>(s_tab, px, py, pz, 20.f, lvl_out, n);
        eval_coarse<kS2, kB2, 2>(s_tab, px, py, pz, 25.f, lvl_out, n);
    }
}

// ---------------- pass B: levels 3-6 via dense-x4 global ----------------
template <int S, int LVL>
__device__ __forceinline__ void eval_mid(
    const u32x4* __restrict__ tab, float px, float py, float pz, float r,
    uint32_t* __restrict__ lvl_out, int n)
{
    const float tx = px * r, ty = py * r, tz = pz * r;
    const float fx = floorf(tx), fy = floorf(ty), fz = floorf(tz);
    const int bx = (int)fx, by = (int)fy, bz = (int)fz;
    const float rx = tx - fx, ry = ty - fy, rz = tz - fz;
    const int gx = bx >> 1;
    const int par = bx & 1;
    const float wx1 = rx, wx0 = 1.f - rx;
    const float wy1 = ry, wy0 = 1.f - ry;
    const float wz1 = rz, wz0 = 1.f - rz;
    float a0 = 0.f, a1 = 0.f;
#pragma unroll
    for (int c = 0; c < 4; ++c) {  // bit1 -> y-corner, bit0 -> z-corner
        const int gidx = (gx * S + (by + ((c >> 1) & 1))) * S + (bz + (c & 1));
        const u32x4 g = tab[gidx];
        const uint32_t lo = par ? g.y : g.x;
        const uint32_t hi = par ? g.z : g.y;
        const float wyz = ((c & 2) ? wy1 : wy0) * ((c & 1) ? wz1 : wz0);
        a0 = fmaf(wyz, fmaf(wx0, bflo(lo), wx1 * bflo(hi)), a0);
        a1 = fmaf(wyz, fmaf(wx0, bfhi(lo), wx1 * bfhi(hi)), a1);
    }
    lvl_out[(size_t)LVL * kPoints + n] =
        bf16_rtne_hi(a0) | (bf16_rtne_hi(a1) << 16);
}

__global__ __launch_bounds__(256) void mid_kernel(
    const float* __restrict__ x, const char* __restrict__ ws,
    uint32_t* __restrict__ lvl_out)
{
    const int b = blockIdx.x;
    const int sub = b >> 11;                 // 0..3 -> level 3..6
    const int chunk = b & 2047;
    const int n0 = chunk * 1024 + threadIdx.x;
#pragma unroll
    for (int k = 0; k < 4; ++k) {
        const int n = n0 + k * 256;
        const float px = fminf(fmaxf(x[3 * n + 0], 0.0f), 1.0f);
        const float py = fminf(fmaxf(x[3 * n + 1], 0.0f), 1.0f);
        const float pz = fminf(fmaxf(x[3 * n + 2], 0.0f), 1.0f);
        if (sub == 0)
            eval_mid<33, 3>((const u32x4*)(ws + kX4Base3), px, py, pz, 32.f, lvl_out, n);
        else if (sub == 1)
            eval_mid<41, 4>((const u32x4*)(ws + kX4Base4), px, py, pz, 40.f, lvl_out, n);
        else if (sub == 2)
            eval_mid<51, 5>((const u32x4*)(ws + kX4Base5), px, py, pz, 50.f, lvl_out, n);
        else
            eval_mid<65, 6>((const u32x4*)(ws + kX4Base6), px, py, pz, 64.f, lvl_out, n);
    }
}

// ------- pass C: levels 7-15 hashed, pinned 2-deep pipeline -------------
// Branchy issue (6 line-lookups/pt, round-6's winning form); consume is
// branch-free via sel bits. sched_barrier(0) walls stop the scheduler
// from sinking loads to uses (round-8 failure: VGPR=28, serialized).
struct PtSt {
    float rx, ry, rz;
    uint32_t sel;              // bit j = half-selector for corner pair j
    uint2 p0, p1, p2, p3;      // corner-pair entries (elo/ehi encoded)
};

__device__ __forceinline__ void issue_pt(
    PtSt& st, const float* __restrict__ x, int n, float r,
    const uint32_t* __restrict__ tab)
{
    const float px = fminf(fmaxf(x[3 * n + 0], 0.f), 1.f);
    const float py = fminf(fmaxf(x[3 * n + 1], 0.f), 1.f);
    const float pz = fminf(fmaxf(x[3 * n + 2], 0.f), 1.f);
    const float tx = px * r, ty = py * r, tz = pz * r;
    const float fx = floorf(tx), fy = floorf(ty), fz = floorf(tz);
    const int bx = (int)fx, by = (int)fy, bz = (int)fz;
    st.rx = tx - fx;  st.ry = ty - fy;  st.rz = tz - fz;
    const uint32_t hy0 = (uint32_t)by * 2654435761u;
    const uint32_t hy1 = (uint32_t)(by + 1) * 2654435761u;
    const uint32_t hz0 = (uint32_t)bz * 805459861u;
    const uint32_t hz1 = (uint32_t)(bz + 1) * 805459861u;
    const uint32_t bxu = (uint32_t)bx, bx1 = bxu + 1u;
    const uint32_t m0 = hy0 ^ hz0, m1 = hy0 ^ hz1;
    const uint32_t m2 = hy1 ^ hz0, m3 = hy1 ^ hz1;
    if ((bx & 1) == 0) {
        // even bx: h(bx+1) = h(bx)^1 -> one aligned 8B pair per corner;
        // sel bit = h&1 resolves which half is the low corner.
        const uint32_t h0 = (bxu ^ m0) & kMask;
        const uint32_t h1 = (bxu ^ m1) & kMask;
        const uint32_t h2 = (bxu ^ m2) & kMask;
        const uint32_t h3 = (bxu ^ m3) & kMask;
        st.sel = (h0 & 1u) | ((h1 & 1u) << 1) |
                 ((h2 & 1u) << 2) | ((h3 & 1u) << 3);
        st.p0 = *reinterpret_cast<const uint2*>(tab + (h0 & ~1u));
        st.p1 = *reinterpret_cast<const uint2*>(tab + (h1 & ~1u));
        st.p2 = *reinterpret_cast<const uint2*>(tab + (h2 & ~1u));
        st.p3 = *reinterpret_cast<const uint2*>(tab + (h3 & ~1u));
    } else {
        // odd bx: unrelated hashes; store (elo,ehi) directly, sel=0.
        st.sel = 0u;
        st.p0.x = tab[(bxu ^ m0) & kMask];  st.p0.y = tab[(bx1 ^ m0) & kMask];
        st.p1.x = tab[(bxu ^ m1) & kMask];  st.p1.y = tab[(bx1 ^ m1) & kMask];
        st.p2.x = tab[(bxu ^ m2) & kMask];  st.p2.y = tab[(bx1 ^ m2) & kMask];
        st.p3.x = tab[(bxu ^ m3) & kMask];  st.p3.y = tab[(bx1 ^ m3) & kMask];
    }
}

__device__ __forceinline__ void consume_pt(
    const PtSt& st, uint32_t* __restrict__ w, int n)
{
    const float wx1 = st.rx, wx0 = 1.f - st.rx;
    const float wy1 = st.ry, wy0 = 1.f - st.ry;
    const float wz1 = st.rz, wz0 = 1.f - st.rz;
    const float w0 = wy0 * wz0, w1 = wy0 * wz1;
    const float w2 = wy1 * wz0, w3 = wy1 * wz1;
    const uint32_t e0 = (st.sel & 1u) ? st.p0.y : st.p0.x;
    const uint32_t f0 = (st.sel & 1u) ? st.p0.x : st.p0.y;
    const uint32_t e1 = (st.sel & 2u) ? st.p1.y : st.p1.x;
    const uint32_t f1 = (st.sel & 2u) ? st.p1.x : st.p1.y;
    const uint32_t e2 = (st.sel & 4u) ? st.p2.y : st.p2.x;
    const uint32_t f2 = (st.sel & 4u) ? st.p2.x : st.p2.y;
    const uint32_t e3 = (st.sel & 8u) ? st.p3.y : st.p3.x;
    const uint32_t f3 = (st.sel & 8u) ? st.p3.x : st.p3.y;
    float a0 = 0.f, a1 = 0.f;
    a0 = fmaf(w0, fmaf(wx0, bflo(e0), wx1 * bflo(f0)), a0);
    a1 = fmaf(w0, fmaf(wx0, bfhi(e0), wx1 * bfhi(f0)), a1);
    a0 = fmaf(w1, fmaf(wx0, bflo(e1), wx1 * bflo(f1)), a0);
    a1 = fmaf(w1, fmaf(wx0, bfhi(e1), wx1 * bfhi(f1)), a1);
    a0 = fmaf(w2, fmaf(wx0, bflo(e2), wx1 * bflo(f2)), a0);
    a1 = fmaf(w2, fmaf(wx0, bfhi(e2), wx1 * bfhi(f2)), a1);
    a0 = fmaf(w3, fmaf(wx0, bflo(e3), wx1 * bflo(f3)), a0);
    a1 = fmaf(w3, fmaf(wx0, bfhi(e3), wx1 * bfhi(f3)), a1);
    w[n] = bf16_rtne_hi(a0) | (bf16_rtne_hi(a1) << 16);
}

__global__ __launch_bounds__(256) void fine_kernel(
    const float* __restrict__ x,
    const uint32_t* __restrict__ packed,
    uint32_t* __restrict__ lvl_out)
{
    const int b = blockIdx.x;
    const int level = 7 + (b >> 11);       // level-at-a-time machine fill
    const int chunk = b & 2047;

    const float r = c_res[level];
    const uint32_t* __restrict__ tab = packed + (size_t)level * kTableSize;
    uint32_t* __restrict__ w = lvl_out + (size_t)level * kPoints;

    const int n0 = chunk * 1024 + threadIdx.x;

    PtSt A, B;
    issue_pt(A, x, n0 + 0 * 256, r, tab);
    issue_pt(B, x, n0 + 1 * 256, r, tab);
    __builtin_amdgcn_sched_barrier(0);     // pin: A,B loads issued above
    consume_pt(A, w, n0 + 0 * 256);
    __builtin_amdgcn_sched_barrier(0);
    issue_pt(A, x, n0 + 2 * 256, r, tab);
    __builtin_amdgcn_sched_barrier(0);     // pin: A2 loads before consume(B)
    consume_pt(B, w, n0 + 1 * 256);
    __builtin_amdgcn_sched_barrier(0);
    issue_pt(B, x, n0 + 3 * 256, r, tab);
    __builtin_amdgcn_sched_barrier(0);     // pin: B3 loads before consume(A2)
    consume_pt(A, w, n0 + 2 * 256);
    __builtin_amdgcn_sched_barrier(0);
    consume_pt(B, w, n0 + 3 * 256);
}

// ---------------- pass 2: level-major bf16 -> [N][32] f32 ----------------
__global__ __launch_bounds__(256) void untile_kernel(
    const uint32_t* __restrict__ lvl_out, float* __restrict__ out)
{
    const int n = blockIdx.x * 256 + threadIdx.x;
    float vals[2 * kLevels];
#pragma unroll
    for (int l = 0; l < kLevels; ++l) {
        const uint32_t u = lvl_out[(size_t)l * kPoints + n];
        vals[2 * l + 0] = bflo(u);
        vals[2 * l + 1] = bfhi(u);
    }
    float4* o4 = reinterpret_cast<float4*>(out + (size_t)n * (2 * kLevels));
#pragma unroll
    for (int kq = 0; kq < 8; ++kq) {
        o4[kq] = make_float4(vals[4 * kq + 0], vals[4 * kq + 1],
                             vals[4 * kq + 2], vals[4 * kq + 3]);
    }
}

// ---------------- fallbacks (round-0/round-2 proven paths) --------------
__device__ __forceinline__ void eval_level(
    float px, float py, float pz, float r,
    const uint32_t* __restrict__ tab, float& a0, float& a1)
{
    const float tx = px * r, ty = py * r, tz = pz * r;
    const float fx = floorf(tx), fy = floorf(ty), fz = floorf(tz);
    const int bx = (int)fx, by = (int)fy, bz = (int)fz;
    const float rx = tx - fx, ry = ty - fy, rz = tz - fz;

    const uint32_t hx0 = (uint32_t)bx;
    const uint32_t hx1 = (uint32_t)(bx + 1);
    const uint32_t hy0 = (uint32_t)by * 2654435761u;
    const uint32_t hy1 = (uint32_t)(by + 1) * 2654435761u;
    const uint32_t hz0 = (uint32_t)bz * 805459861u;
    const uint32_t hz1 = (uint32_t)(bz + 1) * 805459861u;

    const float wx1 = rx, wx0 = 1.0f - rx;
    const float wy1 = ry, wy0 = 1.0f - ry;
    const float wz1 = rz, wz0 = 1.0f - rz;

    a0 = 0.0f; a1 = 0.0f;
#pragma unroll
    for (int c = 0; c < 8; ++c) {
        const uint32_t h = (((c & 4) ? hx1 : hx0) ^
                            ((c & 2) ? hy1 : hy0) ^
                            ((c & 1) ? hz1 : hz0)) & kMask;
        const uint32_t e = tab[h];
        const float w = ((c & 4) ? wx1 : wx0) *
                        ((c & 2) ? wy1 : wy0) *
                        ((c & 1) ? wz1 : wz0);
        a0 = fmaf(w, bflo(e), a0);
        a1 = fmaf(w, bfhi(e), a1);
    }
}

__global__ __launch_bounds__(256) void direct_kernel(
    const float* __restrict__ x,
    const float* __restrict__ tables,
    float* __restrict__ out)
{
    const int n = blockIdx.x * 256 + threadIdx.x;
    float px = fminf(fmaxf(x[3 * n + 0], 0.0f), 1.0f);
    float py = fminf(fmaxf(x[3 * n + 1], 0.0f), 1.0f);
    float pz = fminf(fmaxf(x[3 * n + 2], 0.0f), 1.0f);

    const float res_tab[kLevels] = {
        16.f, 20.f, 25.f, 32.f, 40.f, 50.f, 64.f, 80.f,
        101.f, 128.f, 161.f, 203.f, 256.f, 322.f, 406.f, 512.f};

    float acc[2 * kLevels];
#pragma unroll
    for (int l = 0; l < kLevels; ++l) {
        const float r = res_tab[l];
        const float tx = px * r, ty = py * r, tz = pz * r;
        const float fx = floorf(tx), fy = floorf(ty), fz = floorf(tz);
        const int bx = (int)fx, by = (int)fy, bz = (int)fz;
        const float rx = tx - fx, ry = ty - fy, rz = tz - fz;
        const uint32_t hx0 = (uint32_t)bx;
        const uint32_t hx1 = (uint32_t)(bx + 1);
        const uint32_t hy0 = (uint32_t)by * 2654435761u;
        const uint32_t hy1 = (uint32_t)(by + 1) * 2654435761u;
        const uint32_t hz0 = (uint32_t)bz * 805459861u;
        const uint32_t hz1 = (uint32_t)(bz + 1) * 805459861u;
        const float wx1 = rx, wx0 = 1.0f - rx;
        const float wy1 = ry, wy0 = 1.0f - ry;
        const float wz1 = rz, wz0 = 1.0f - rz;
        const float2* __restrict__ tab =
            reinterpret_cast<const float2*>(tables) + (size_t)l * kTableSize;
        float a0 = 0.0f, a1 = 0.0f;
#pragma unroll
        for (int c = 0; c < 8; ++c) {
            const uint32_t h = (((c & 4) ? hx1 : hx0) ^
                                ((c & 2) ? hy1 : hy0) ^
                                ((c & 1) ? hz1 : hz0)) & kMask;
            const float2 e = tab[h];
            const float w = ((c & 4) ? wx1 : wx0) *
                            ((c & 2) ? wy1 : wy0) *
                            ((c & 1) ? wz1 : wz0);
            a0 = fmaf(w, e.x, a0);
            a1 = fmaf(w, e.y, a1);
        }
        acc[2 * l + 0] = a0;
        acc[2 * l + 1] = a1;
    }
    float4* o4 = reinterpret_cast<float4*>(out + (size_t)n * (2 * kLevels));
#pragma unroll
    for (int kq = 0; kq < 8; ++kq) {
        o4[kq] = make_float4(acc[4 * kq + 0], acc[4 * kq + 1],
                             acc[4 * kq + 2], acc[4 * kq + 3]);
    }
}

__global__ __launch_bounds__(256) void direct_packed_kernel(
    const float* __restrict__ x,
    const uint32_t* __restrict__ packed,
    float* __restrict__ out)
{
    const int n = blockIdx.x * 256 + threadIdx.x;
    float px = fminf(fmaxf(x[3 * n + 0], 0.0f), 1.0f);
    float py = fminf(fmaxf(x[3 * n + 1], 0.0f), 1.0f);
    float pz = fminf(fmaxf(x[3 * n + 2], 0.0f), 1.0f);

    const float res_tab[kLevels] = {
        16.f, 20.f, 25.f, 32.f, 40.f, 50.f, 64.f, 80.f,
        101.f, 128.f, 161.f, 203.f, 256.f, 322.f, 406.f, 512.f};

    float acc[2 * kLevels];
#pragma unroll
    for (int l = 0; l < kLevels; ++l) {
        float a0, a1;
        eval_level(px, py, pz, res_tab[l],
                   packed + (size_t)l * kTableSize, a0, a1);
        acc[2 * l + 0] = a0;
        acc[2 * l + 1] = a1;
    }
    float4* o4 = reinterpret_cast<float4*>(out + (size_t)n * (2 * kLevels));
#pragma unroll
    for (int kq = 0; kq < 8; ++kq) {
        o4[kq] = make_float4(acc[4 * kq + 0], acc[4 * kq + 1],
                             acc[4 * kq + 2], acc[4 * kq + 3]);
    }
}

extern "C" void kernel_launch(void* const* d_in, const int* in_sizes, int n_in,
                              void* d_out, int out_size, void* d_ws, size_t ws_size,
                              hipStream_t stream) {
    const float* x = (const float*)d_in[0];       // [2^21, 3] f32
    const float* tables = (const float*)d_in[1];  // [16, 2^19, 2] f32
    float* out = (float*)d_out;                   // [2^21, 32] f32

    if (ws_size >= kPackedBytes + kLvlOutBytes) {
        char* ws = (char*)d_ws;
        uint32_t* packed = (uint32_t*)ws;
        uint32_t* lvl_out = (uint32_t*)(ws + kPackedBytes);
        uint32_t* dense012 = (uint32_t*)ws;  // overlays packed[0..2] (unused)

        hipLaunchKernelGGL(pack_tables_kernel,
                           dim3((kLevels * kTableSize / 2) / 256), dim3(256),
                           0, stream, tables, packed);
        // builds overwrite the packed[0..2] region only; readers of
        // packed[3..6] (build_x4) and packed[7..15] (fine) are untouched.
        hipLaunchKernelGGL(build_dense012_kernel,
                           dim3((kNDense + 255) / 256), dim3(256),
                           0, stream, tables, dense012);
        hipLaunchKernelGGL(build_x4_kernel,
                           dim3((kGTot + 255) / 256), dim3(256),
                           0, stream, packed, ws);
        // pass A: levels 0-2 (LDS), 1024 blocks x 512 thr x 4 pts
        hipLaunchKernelGGL(coarse_kernel, dim3(kPoints / 2048), dim3(512),
                           0, stream, x, dense012, lvl_out);
        // pass B: levels 3-6 (dense-x4), 4 x 2048 blocks
        hipLaunchKernelGGL(mid_kernel, dim3(4 * 2048), dim3(256),
                           0, stream, x, (const char*)ws, lvl_out);
        // pass C: levels 7-15 (hashed, pinned 2-deep pipe), 9 x 2048 blocks
        hipLaunchKernelGGL(fine_kernel, dim3(9 * 2048), dim3(256),
                           0, stream, x, packed, lvl_out);
        // pass 2
        hipLaunchKernelGGL(untile_kernel, dim3(kPoints / 256), dim3(256),
                           0, stream, lvl_out, out);
    } else if (ws_size >= kPackedBytes) {
        uint32_t* packed = (uint32_t*)d_ws;
        hipLaunchKernelGGL(pack_tables_kernel,
                           dim3((kLevels * kTableSize / 2) / 256), dim3(256),
                           0, stream, tables, packed);
        hipLaunchKernelGGL(direct_packed_kernel, dim3(kPoints / 256), dim3(256),
                           0, stream, x, packed, out);
    } else {
        hipLaunchKernelGGL(direct_kernel, dim3(kPoints / 256), dim3(256),
                           0, stream, x, tables, out);
    }
}